// Round 8
// baseline (2332.671 us; speedup 1.0000x reference)
//
#include <hip/hip_runtime.h>
#include <hip/hip_bf16.h>
#include <stdint.h>

#define B_  128
#define T_  512
#define H_  1024
#define E_  1024
#define NC_ 10
#define NT_ (B_*T_)   // 65536

#define BAR_DEAD  0
#define CANARY    0xFFFFFFFFu

typedef __attribute__((ext_vector_type(8))) short  short8;
typedef __attribute__((ext_vector_type(4))) float  f32x4;

static __device__ __forceinline__ float bf2f(ushort u){
  union { uint u; float f; } v; v.u = ((uint)u) << 16; return v.f;
}
static __device__ __forceinline__ ushort f2bf(float f){
  union { float f; uint u; } v; v.f = f;
  uint u = v.u;
  uint lsb = (u >> 16) & 1u;
  u += 0x7fffu + lsb;          // round-to-nearest-even
  return (ushort)(u >> 16);
}
static __device__ __forceinline__ float fsig(float x){ return 1.f / (1.f + __expf(-x)); }
static __device__ __forceinline__ float ftanh(float x){
  float e = __expf(2.f * x);
  return 1.f - 2.f / (e + 1.f);
}

// async global->LDS, 16B per lane. LDS dst wave-uniform; HW adds lane*16. Global src per-lane.
#define ASYNC_COPY16(gsrc, ldsdst) \
  __builtin_amdgcn_global_load_lds((const __attribute__((address_space(1))) uint32_t*)(gsrc), \
                                   (__attribute__((address_space(3))) uint32_t*)(ldsdst), 16, 0, 0)

static __device__ __forceinline__ long long rtclock(){
  return (long long)__builtin_amdgcn_s_memrealtime();
}

// ---------------- alive[t] = cumprod(colsum(x) != 0) ----------------
__global__ __launch_bounds__(512) void k_alive(const int* __restrict__ x,
                                               float* __restrict__ alive,
                                               float* __restrict__ aliveSum){
  __shared__ float fl[T_];
  int t = threadIdx.x;
  int s = 0;
  for (int b = 0; b < B_; ++b) s += x[b*T_ + t];
  fl[t] = (s != 0) ? 1.f : 0.f;
  __syncthreads();
  if (t == 0){
    float run = 1.f, sum = 0.f;
    for (int i = 0; i < T_; ++i){ run *= fl[i]; alive[i] = run; sum += run; }
    aliveSum[0] = sum;
  }
}

// ---------------- weight conversion: Wc -> bf16 (stride 2048) ----------------
__global__ __launch_bounds__(256) void k_convW(const float* __restrict__ Wc,
                                               ushort* __restrict__ Wcb){
  int idx = blockIdx.x*256 + threadIdx.x;
  if (idx < 1024*2048) Wcb[idx] = f2bf(Wc[idx]);
}

// ---------------- gather + bf16 convert: XB[n][k] = bf16(embed[x[n]][k]) ----------------
__global__ __launch_bounds__(256) void k_gather(const int* __restrict__ x,
                                                const float* __restrict__ embed,
                                                ushort* __restrict__ XB){
  size_t g = (size_t)blockIdx.x*256 + threadIdx.x;
  const size_t total = (size_t)NT_ * 128;   // 8-element chunks
  for (; g < total; g += (size_t)gridDim.x*256){
    size_t row = g >> 7;
    int cj = (int)(g & 127) * 8;
    int tok = x[row];
    const float* src = embed + (size_t)tok*1024 + cj;
    float4 v0 = *(const float4*)src;
    float4 v1 = *(const float4*)(src + 4);
    uint4 o;
    o.x = (uint)f2bf(v0.x) | ((uint)f2bf(v0.y) << 16);
    o.y = (uint)f2bf(v0.z) | ((uint)f2bf(v0.w) << 16);
    o.z = (uint)f2bf(v1.x) | ((uint)f2bf(v1.y) << 16);
    o.w = (uint)f2bf(v1.z) | ((uint)f2bf(v1.w) << 16);
    *(uint4*)&XB[g*8] = o;
  }
}

// ---------------- big GEMM: A2[t][b][o] = bf16( sum_k XB[n][k]*Wcb[o][k] + bc[o] ), n=b*T+t ----------------
__global__ __launch_bounds__(256) void k_gemmA(const ushort* __restrict__ XB,
                                               const ushort* __restrict__ Wcb,
                                               const float* __restrict__ bc,
                                               ushort* __restrict__ A2){
  __shared__ ushort As[128*64];
  __shared__ ushort Bs[128*64];
  const int bx = blockIdx.x;
  const int nt = bx & 7, mt = bx >> 3;
  const int tid = threadIdx.x, w = tid >> 6, l = tid & 63;
  const int wm = w >> 1, wn = w & 1;
  f32x4 acc[4][4];
  #pragma unroll
  for (int i = 0; i < 4; ++i)
    #pragma unroll
    for (int j = 0; j < 4; ++j) acc[i][j] = (f32x4){0.f,0.f,0.f,0.f};

  const int lrow = l >> 3, lcol = (l & 7) * 8;
  for (int kt = 0; kt < 16; ++kt){
    #pragma unroll
    for (int i = 0; i < 4; ++i){
      int cc = i*4 + w;
      const ushort* ga = XB  + (size_t)(mt*128 + cc*8 + lrow)*1024 + kt*64 + lcol;
      ASYNC_COPY16(ga, (char*)As + cc*1024);
      const ushort* gb = Wcb + (size_t)(nt*128 + cc*8 + lrow)*2048 + kt*64 + lcol;
      ASYNC_COPY16(gb, (char*)Bs + cc*1024);
    }
    __syncthreads();
    #pragma unroll
    for (int ks = 0; ks < 2; ++ks){
      short8 a[4], b[4];
      #pragma unroll
      for (int mi = 0; mi < 4; ++mi)
        a[mi] = *(const short8*)&As[(wm*64 + mi*16 + (l & 15))*64 + ks*32 + (l >> 4)*8];
      #pragma unroll
      for (int ni = 0; ni < 4; ++ni)
        b[ni] = *(const short8*)&Bs[(wn*64 + ni*16 + (l & 15))*64 + ks*32 + (l >> 4)*8];
      #pragma unroll
      for (int mi = 0; mi < 4; ++mi)
        #pragma unroll
        for (int ni = 0; ni < 4; ++ni)
          acc[mi][ni] = __builtin_amdgcn_mfma_f32_16x16x32_bf16(a[mi], b[ni], acc[mi][ni], 0, 0, 0);
    }
    __syncthreads();
  }
  const int col0 = nt*128 + wn*64;
  const int row0 = mt*128 + wm*64;
  #pragma unroll
  for (int ni = 0; ni < 4; ++ni){
    int col = col0 + ni*16 + (l & 15);
    float bias = bc[col];
    #pragma unroll
    for (int mi = 0; mi < 4; ++mi)
      #pragma unroll
      for (int r = 0; r < 4; ++r){
        int row = row0 + mi*16 + (l >> 4)*4 + r;   // n = b*T + t
        int b_i = row >> 9, t_i = row & 511;
        A2[((size_t)t_i*B_ + b_i)*1024 + col] = f2bf(acc[mi][ni][r] + bias);
      }
  }
}

// ---------------- gate x-part: G0/G2[t*B+b] = sum_k XB[n][k]*Wg[j][k] + bg[j], j in {0,2} ----------------
__global__ __launch_bounds__(256) void k_gateG(const ushort* __restrict__ XB,
                                               const float* __restrict__ Wg,
                                               const float* __restrict__ bgv,
                                               float* __restrict__ G0,
                                               float* __restrict__ G2){
  int tid = threadIdx.x, w = tid >> 6, l = tid & 63;
  size_t n = (size_t)blockIdx.x*4 + w;
  const ushort* xr = XB + n*1024;
  int k0 = l * 16;
  float s0 = 0.f, s2 = 0.f;
  #pragma unroll
  for (int h = 0; h < 2; ++h){
    short8 xv = *(const short8*)&xr[k0 + h*8];
    #pragma unroll
    for (int e = 0; e < 8; ++e){
      float xf = bf2f((ushort)xv[e]);
      s0 += xf * Wg[(size_t)0*2048 + k0 + h*8 + e];
      s2 += xf * Wg[(size_t)2*2048 + k0 + h*8 + e];
    }
  }
  for (int off = 32; off; off >>= 1){ s0 += __shfl_xor(s0, off, 64); s2 += __shfl_xor(s2, off, 64); }
  if (l == 0){
    int b_i = (int)(n >> 9), t_i = (int)(n & 511);
    G0[(size_t)t_i*B_ + b_i] = s0 + bgv[0];
    G2[(size_t)t_i*B_ + b_i] = s2 + bgv[2];
  }
}

// ---------------- persistent recurrence: data-is-the-flag, per-step h slots ----------------
// 256 WGs: bg = blk&7 (16 batch rows), oc = blk>>3 (32 out cols). ~120KB LDS ->
// 1 WG/CU; grid==256==#CUs => co-resident. Whh slice + gate weights LDS-resident.
// hT[512 slots][B][1024] (aliases dead XB region): slot 0 = h0 = zeros, slots 1..511
// pre-filled with CANARY (impossible as f2bf output since |h|<1). Producers write h
// as relaxed agent-scope 4B atomic stores (write-through to IF, R3/R7-proven).
// Consumers poll their 8 sc1 16B loads directly, retrying chunks still showing
// CANARY -- no flags, no fences, ONE IF round trip per step. Time-bounded retries
// + sticky dead flag: worst case fast wrong answer, never a wedge.
__global__ __launch_bounds__(256, 1) void k_recur(const ushort* __restrict__ Wcb,
                                                  const float*  __restrict__ Wg,
                                                  const ushort* __restrict__ A2,
                                                  const float*  __restrict__ G0,
                                                  const float*  __restrict__ G2,
                                                  const float*  __restrict__ alive,
                                                  ushort* __restrict__ hT,      // [512][B][1024]
                                                  float*  __restrict__ hsum,    // [B][1024]
                                                  uint*   __restrict__ bar){
  __shared__ ushort WhhS[32*1024];        // 64KB, XOR-swizzled rows (out-cols)
  __shared__ ushort hS[4*16*256];         // 32KB, [wave][row][k-slice], swizzled
  __shared__ ushort wgS[3*1032];          // 6.2KB: padded rows (wg0, wg2, zeros)
  __shared__ float  upart[2][4][16][33];  // 16.9KB, parity-double-buffered
  __shared__ float  gpart[2][4][16][2];   // 1KB

  const int blk = blockIdx.x;
  const int bg = blk & 7, oc = blk >> 3;
  const int tid = threadIdx.x, w = tid >> 6, l = tid & 63;
  const long long tstart = rtclock();

  // ---- prologue: Whh slice -> LDS (swizzled write) ----
  #pragma unroll
  for (int it = 0; it < 16; ++it){
    int ch = it*256 + tid;            // 4096 chunks of 16B
    int ci = ch >> 7;                 // local col 0..31
    int kb = (ch & 127) * 16;         // byte in 2048B row
    const char* src = (const char*)Wcb + (((size_t)(oc*32 + ci)*2048 + 1024) * 2) + kb;
    uint4 v = *(const uint4*)src;
    *(uint4*)((char*)WhhS + ci*2048 + (kb ^ ((ci & 7) << 4))) = v;
  }
  for (int it = 0; it < 13; ++it){
    int idx = it*256 + tid;           // 0..3095
    if (idx < 3096){
      int j = idx / 1032, k = idx - j*1032;
      float v = 0.f;
      if (k < 1024){
        if (j == 0)      v = Wg[(size_t)0*2048 + 1024 + k];
        else if (j == 1) v = Wg[(size_t)2*2048 + 1024 + k];
      }
      wgS[idx] = f2bf(v);
    }
  }
  __syncthreads();

  const int r_ep = tid >> 4;                 // epilogue row 0..15
  const int c0   = (tid & 15) * 2;           // epilogue col pair
  const int b_ep = bg*16 + r_ep;
  const int lr   = l & 15, lk = (l >> 4) * 8;
  const int gsel = (lr == 0) ? 0 : (lr == 2 ? 2064 : 4128);   // byte offset into wgS (padded rows)
  float hs0 = 0.f, hs1 = 0.f;

  uint* dead = &bar[BAR_DEAD];
  bool bail = false;

  // prefetch step-0 inputs into registers
  uint  av  = *(const uint*)&A2[((size_t)0*B_ + b_ep)*1024 + oc*32 + c0];
  float gx0 = G0[b_ep], gx2 = G2[b_ep];
  float au  = alive[0];

  for (int t = 0; t < T_; ++t){
    // ---- poll+load wave-private h K-slice: sc1 16B loads, retry CANARY chunks ----
    const ushort* hprev = hT + (size_t)t*(B_*H_) + (size_t)bg*16*1024;
    const char* ap[8];
    #pragma unroll
    for (int j = 0; j < 8; ++j){
      int r = j*2 + (l >> 5);
      int s = l & 31;
      ap[j] = (const char*)(hprev + (size_t)r*1024 + w*256 + ((s ^ (r & 7)) * 8));
    }
    uint4 hv[8];
    #pragma unroll
    for (int j = 0; j < 8; ++j)
      asm volatile("global_load_dwordx4 %0, %1, off sc1" : "=v"(hv[j]) : "v"(ap[j]));
    asm volatile("s_waitcnt vmcnt(0)" ::: "memory");
    uint pend = 0;
    #pragma unroll
    for (int j = 0; j < 8; ++j)
      if (hv[j].x == CANARY || hv[j].y == CANARY || hv[j].z == CANARY || hv[j].w == CANARY)
        pend |= (1u << j);
    if (!bail && __any((int)(pend != 0u))){
      long long t0 = rtclock();
      uint it = 0;
      while (__any((int)(pend != 0u))){
        #pragma unroll
        for (int j = 0; j < 8; ++j)
          if (pend & (1u << j))
            asm volatile("global_load_dwordx4 %0, %1, off sc1" : "=v"(hv[j]) : "v"(ap[j]));
        asm volatile("s_waitcnt vmcnt(0)" ::: "memory");
        #pragma unroll
        for (int j = 0; j < 8; ++j)
          if ((pend & (1u << j)) &&
              !(hv[j].x == CANARY || hv[j].y == CANARY || hv[j].z == CANARY || hv[j].w == CANARY))
            pend &= ~(1u << j);
        if ((++it & 15u) == 0u){
          if (__hip_atomic_load(dead, __ATOMIC_RELAXED, __HIP_MEMORY_SCOPE_AGENT)){ bail = true; break; }
          long long now = rtclock();
          if (now - t0 > 200000LL || now - tstart > 30000000LL){
            if (tid == 0) __hip_atomic_store(dead, 1u, __ATOMIC_RELAXED, __HIP_MEMORY_SCOPE_AGENT);
            bail = true; break;
          }
        }
      }
    }
    #pragma unroll
    for (int j = 0; j < 8; ++j)
      *(uint4*)((char*)hS + w*8192 + j*1024 + (size_t)l*16) = hv[j];

    // ---- u + gates via MFMA (K split across waves) ----
    const int p = t & 1;
    f32x4 uacc0 = (f32x4){0.f,0.f,0.f,0.f};
    f32x4 uacc1 = (f32x4){0.f,0.f,0.f,0.f};
    f32x4 gacc  = (f32x4){0.f,0.f,0.f,0.f};
    #pragma unroll
    for (int ks = 0; ks < 8; ++ks){
      int kbh  = (ks*32 + lk) * 2;
      int swzh = kbh ^ ((lr & 7) << 4);
      short8 a  = *(const short8*)((const char*)hS + w*8192 + lr*512 + swzh);
      int kbw  = (w*256 + ks*32 + lk) * 2;
      int swzw = kbw ^ ((lr & 7) << 4);
      short8 b0 = *(const short8*)((const char*)WhhS + lr*2048 + swzw);
      short8 b1 = *(const short8*)((const char*)WhhS + (16 + lr)*2048 + swzw);
      short8 gv = *(const short8*)((const char*)wgS + gsel + kbw);
      uacc0 = __builtin_amdgcn_mfma_f32_16x16x32_bf16(a, b0, uacc0, 0, 0, 0);
      uacc1 = __builtin_amdgcn_mfma_f32_16x16x32_bf16(a, b1, uacc1, 0, 0, 0);
      gacc  = __builtin_amdgcn_mfma_f32_16x16x32_bf16(a, gv, gacc,  0, 0, 0);
    }
    #pragma unroll
    for (int r4 = 0; r4 < 4; ++r4){
      int m = (l >> 4)*4 + r4;
      upart[p][w][m][lr]      = uacc0[r4];
      upart[p][w][m][16 + lr] = uacc1[r4];
      if (lr == 0) gpart[p][w][m][0] = gacc[r4];
      if (lr == 2) gpart[p][w][m][1] = gacc[r4];
    }
    __syncthreads();

    // ---- epilogue: 2 outputs per thread ----
    float u0 = upart[p][0][r_ep][c0]   + upart[p][1][r_ep][c0]   + upart[p][2][r_ep][c0]   + upart[p][3][r_ep][c0];
    float u1 = upart[p][0][r_ep][c0+1] + upart[p][1][r_ep][c0+1] + upart[p][2][r_ep][c0+1] + upart[p][3][r_ep][c0+1];
    float gp0 = gpart[p][0][r_ep][0] + gpart[p][1][r_ep][0] + gpart[p][2][r_ep][0] + gpart[p][3][r_ep][0];
    float gp2 = gpart[p][0][r_ep][1] + gpart[p][1][r_ep][1] + gpart[p][2][r_ep][1] + gpart[p][3][r_ep][1];
    float gi = fsig(gx0 + gp0);
    float go = fsig(gx2 + gp2);
    float a0 = bf2f((ushort)(av & 0xffffu));
    float a1 = bf2f((ushort)(av >> 16));
    float hn0 = go * ftanh(gi * ftanh(a0 + u0));
    float hn1 = go * ftanh(gi * ftanh(a1 + u1));
    hs0 += au * hn0;
    hs1 += au * hn1;
    // write-through h store to slot (t+1) (slot 512 wraps to 0 -- never read again)
    uint hv2 = (uint)f2bf(hn0) | ((uint)f2bf(hn1) << 16);
    uint* hdst = (uint*)&hT[(size_t)((t + 1) & 511)*(B_*H_) + (size_t)b_ep*1024 + oc*32 + c0];
    __hip_atomic_store(hdst, hv2, __ATOMIC_RELAXED, __HIP_MEMORY_SCOPE_AGENT);

    // ---- prefetch next step's read-only inputs ----
    int tn = (t < T_-1) ? t + 1 : t;
    av  = *(const uint*)&A2[((size_t)tn*B_ + b_ep)*1024 + oc*32 + c0];
    gx0 = G0[(size_t)tn*B_ + b_ep];
    gx2 = G2[(size_t)tn*B_ + b_ep];
    au  = alive[tn];
  }

  hsum[(size_t)b_ep*1024 + oc*32 + c0]     = hs0;
  hsum[(size_t)b_ep*1024 + oc*32 + c0 + 1] = hs1;
}

// ---------------- output: out[b][c] = dot(hsum[b], Wo[c]) / aliveSum + bo[c] ----------------
__global__ __launch_bounds__(256) void k_out(const float* __restrict__ hsum,
                                             const float* __restrict__ Wo,
                                             const float* __restrict__ bo,
                                             const float* __restrict__ aliveSum,
                                             float* __restrict__ out){
  __shared__ float accs[NC_];
  int b = blockIdx.x, tid = threadIdx.x;
  if (tid < NC_) accs[tid] = 0.f;
  __syncthreads();
  int k0 = tid * 4;
  float4 hv = *(const float4*)&hsum[(size_t)b*1024 + k0];
  float part[NC_];
  #pragma unroll
  for (int c = 0; c < NC_; ++c){
    const float* wr = Wo + (size_t)c*1024 + k0;
    part[c] = hv.x*wr[0] + hv.y*wr[1] + hv.z*wr[2] + hv.w*wr[3];
  }
  #pragma unroll
  for (int c = 0; c < NC_; ++c){
    float v = part[c];
    for (int off = 32; off; off >>= 1) v += __shfl_xor(v, off, 64);
    if ((tid & 63) == 0) atomicAdd(&accs[c], v);
  }
  __syncthreads();
  if (tid < NC_) out[b*NC_ + tid] = accs[tid] / aliveSum[0] + bo[tid];
}

extern "C" void kernel_launch(void* const* d_in, const int* in_sizes, int n_in,
                              void* d_out, int out_size, void* d_ws, size_t ws_size,
                              hipStream_t stream){
  const int*   x     = (const int*)  d_in[0];
  const float* embed = (const float*)d_in[1];
  const float* Wg    = (const float*)d_in[2];
  const float* bg    = (const float*)d_in[3];
  const float* Wc    = (const float*)d_in[4];
  const float* bc    = (const float*)d_in[5];
  const float* Wo    = (const float*)d_in[6];
  const float* bo    = (const float*)d_in[7];
  float* out = (float*)d_out;

  // workspace layout (~274 MB). hT (per-step h slots, 512 x 256KB = 134.2MB)
  // ALIASES XB: XB is dead after k_gemmA/k_gateG; memsets below are stream-ordered
  // after those kernels.
  char* p = (char*)d_ws;
  ushort* XB    = (ushort*)p;
  ushort* hT    = (ushort*)p;  p += (size_t)NT_*1024*2;     // 134.2MB (XB | hT)
  ushort* A2    = (ushort*)p;  p += (size_t)NT_*1024*2;     // 134.2MB  [t][b][1024]
  ushort* Wcb   = (ushort*)p;  p += (size_t)1024*2048*2;    // 4MB
  float*  G0    = (float*)p;   p += (size_t)NT_*4;          // 256KB
  float*  G2    = (float*)p;   p += (size_t)NT_*4;          // 256KB
  float*  hsum  = (float*)p;   p += (size_t)B_*H_*4;        // 512KB
  float*  alive = (float*)p;   p += (size_t)T_*4;
  float*  aliveSum = (float*)p; p += 256;
  uint*   bar   = (uint*)p;    p += 4*1024;                 // dead flag

  (void)ws_size; (void)in_sizes; (void)n_in; (void)out_size;

  hipMemsetAsync(bar, 0, 4*1024, stream);

  k_alive <<<1,    512, 0, stream>>>(x, alive, aliveSum);
  k_convW <<<8192, 256, 0, stream>>>(Wc, Wcb);
  k_gather<<<4096, 256, 0, stream>>>(x, embed, XB);
  k_gemmA <<<4096, 256, 0, stream>>>(XB, Wcb, bc, A2);
  k_gateG <<<16384,256, 0, stream>>>(XB, Wg, bg, G0, G2);

  // XB is now dead; initialize hT in its place (stream-ordered):
  hipMemsetAsync(hT, 0, (size_t)B_*H_*2, stream);                                   // slot 0: h0 = 0
  hipMemsetAsync(hT + (size_t)B_*H_, 0xFF, (size_t)511*B_*H_*2, stream);            // slots 1..511: canary

  k_recur<<<256, 256, 0, stream>>>(Wcb, Wg, A2, G0, G2, alive, hT, hsum, bar);

  k_out<<<B_, 256, 0, stream>>>(hsum, Wo, bo, aliveSum, out);
}

// Round 10
// 2219.718 us; speedup vs baseline: 1.0509x; 1.0509x over previous
//
#include <hip/hip_runtime.h>
#include <hip/hip_bf16.h>
#include <stdint.h>

#define B_  128
#define T_  512
#define H_  1024
#define E_  1024
#define NC_ 10
#define NT_ (B_*T_)   // 65536

#define BAR_DEAD  0
#define CANARY    0xFFFFFFFFu
#define NSLOT     8

typedef __attribute__((ext_vector_type(8))) short  short8;
typedef __attribute__((ext_vector_type(4))) float  f32x4;

static __device__ __forceinline__ float bf2f(ushort u){
  union { uint u; float f; } v; v.u = ((uint)u) << 16; return v.f;
}
static __device__ __forceinline__ ushort f2bf(float f){
  union { float f; uint u; } v; v.f = f;
  uint u = v.u;
  uint lsb = (u >> 16) & 1u;
  u += 0x7fffu + lsb;          // round-to-nearest-even
  return (ushort)(u >> 16);
}
static __device__ __forceinline__ float fsig(float x){ return 1.f / (1.f + __expf(-x)); }
static __device__ __forceinline__ float ftanh(float x){
  float e = __expf(2.f * x);
  return 1.f - 2.f / (e + 1.f);
}

// async global->LDS, 16B per lane. LDS dst wave-uniform; HW adds lane*16. Global src per-lane.
#define ASYNC_COPY16(gsrc, ldsdst) \
  __builtin_amdgcn_global_load_lds((const __attribute__((address_space(1))) uint32_t*)(gsrc), \
                                   (__attribute__((address_space(3))) uint32_t*)(ldsdst), 16, 0, 0)

static __device__ __forceinline__ long long rtclock(){
  return (long long)__builtin_amdgcn_s_memrealtime();
}

// ---------------- alive[t] = cumprod(colsum(x) != 0) ----------------
__global__ __launch_bounds__(512) void k_alive(const int* __restrict__ x,
                                               float* __restrict__ alive,
                                               float* __restrict__ aliveSum){
  __shared__ float fl[T_];
  int t = threadIdx.x;
  int s = 0;
  for (int b = 0; b < B_; ++b) s += x[b*T_ + t];
  fl[t] = (s != 0) ? 1.f : 0.f;
  __syncthreads();
  if (t == 0){
    float run = 1.f, sum = 0.f;
    for (int i = 0; i < T_; ++i){ run *= fl[i]; alive[i] = run; sum += run; }
    aliveSum[0] = sum;
  }
}

// ---------------- weight conversion: Wc -> bf16 (stride 2048) ----------------
__global__ __launch_bounds__(256) void k_convW(const float* __restrict__ Wc,
                                               ushort* __restrict__ Wcb){
  int idx = blockIdx.x*256 + threadIdx.x;
  if (idx < 1024*2048) Wcb[idx] = f2bf(Wc[idx]);
}

// ---------------- gather + bf16 convert: XB[n][k] = bf16(embed[x[n]][k]) ----------------
__global__ __launch_bounds__(256) void k_gather(const int* __restrict__ x,
                                                const float* __restrict__ embed,
                                                ushort* __restrict__ XB){
  size_t g = (size_t)blockIdx.x*256 + threadIdx.x;
  const size_t total = (size_t)NT_ * 128;   // 8-element chunks
  for (; g < total; g += (size_t)gridDim.x*256){
    size_t row = g >> 7;
    int cj = (int)(g & 127) * 8;
    int tok = x[row];
    const float* src = embed + (size_t)tok*1024 + cj;
    float4 v0 = *(const float4*)src;
    float4 v1 = *(const float4*)(src + 4);
    uint4 o;
    o.x = (uint)f2bf(v0.x) | ((uint)f2bf(v0.y) << 16);
    o.y = (uint)f2bf(v0.z) | ((uint)f2bf(v0.w) << 16);
    o.z = (uint)f2bf(v1.x) | ((uint)f2bf(v1.y) << 16);
    o.w = (uint)f2bf(v1.z) | ((uint)f2bf(v1.w) << 16);
    *(uint4*)&XB[g*8] = o;
  }
}

// ---------------- big GEMM: A2[t][b][o] = bf16( sum_k XB[n][k]*Wcb[o][k] + bc[o] ), n=b*T+t ----------------
__global__ __launch_bounds__(256) void k_gemmA(const ushort* __restrict__ XB,
                                               const ushort* __restrict__ Wcb,
                                               const float* __restrict__ bc,
                                               ushort* __restrict__ A2){
  __shared__ ushort As[128*64];
  __shared__ ushort Bs[128*64];
  const int bx = blockIdx.x;
  const int nt = bx & 7, mt = bx >> 3;
  const int tid = threadIdx.x, w = tid >> 6, l = tid & 63;
  const int wm = w >> 1, wn = w & 1;
  f32x4 acc[4][4];
  #pragma unroll
  for (int i = 0; i < 4; ++i)
    #pragma unroll
    for (int j = 0; j < 4; ++j) acc[i][j] = (f32x4){0.f,0.f,0.f,0.f};

  const int lrow = l >> 3, lcol = (l & 7) * 8;
  for (int kt = 0; kt < 16; ++kt){
    #pragma unroll
    for (int i = 0; i < 4; ++i){
      int cc = i*4 + w;
      const ushort* ga = XB  + (size_t)(mt*128 + cc*8 + lrow)*1024 + kt*64 + lcol;
      ASYNC_COPY16(ga, (char*)As + cc*1024);
      const ushort* gb = Wcb + (size_t)(nt*128 + cc*8 + lrow)*2048 + kt*64 + lcol;
      ASYNC_COPY16(gb, (char*)Bs + cc*1024);
    }
    __syncthreads();
    #pragma unroll
    for (int ks = 0; ks < 2; ++ks){
      short8 a[4], b[4];
      #pragma unroll
      for (int mi = 0; mi < 4; ++mi)
        a[mi] = *(const short8*)&As[(wm*64 + mi*16 + (l & 15))*64 + ks*32 + (l >> 4)*8];
      #pragma unroll
      for (int ni = 0; ni < 4; ++ni)
        b[ni] = *(const short8*)&Bs[(wn*64 + ni*16 + (l & 15))*64 + ks*32 + (l >> 4)*8];
      #pragma unroll
      for (int mi = 0; mi < 4; ++mi)
        #pragma unroll
        for (int ni = 0; ni < 4; ++ni)
          acc[mi][ni] = __builtin_amdgcn_mfma_f32_16x16x32_bf16(a[mi], b[ni], acc[mi][ni], 0, 0, 0);
    }
    __syncthreads();
  }
  const int col0 = nt*128 + wn*64;
  const int row0 = mt*128 + wm*64;
  #pragma unroll
  for (int ni = 0; ni < 4; ++ni){
    int col = col0 + ni*16 + (l & 15);
    float bias = bc[col];
    #pragma unroll
    for (int mi = 0; mi < 4; ++mi)
      #pragma unroll
      for (int r = 0; r < 4; ++r){
        int row = row0 + mi*16 + (l >> 4)*4 + r;   // n = b*T + t
        int b_i = row >> 9, t_i = row & 511;
        A2[((size_t)t_i*B_ + b_i)*1024 + col] = f2bf(acc[mi][ni][r] + bias);
      }
  }
}

// ---------------- gate x-part: G0/G2[t*B+b] = sum_k XB[n][k]*Wg[j][k] + bg[j], j in {0,2} ----------------
__global__ __launch_bounds__(256) void k_gateG(const ushort* __restrict__ XB,
                                               const float* __restrict__ Wg,
                                               const float* __restrict__ bgv,
                                               float* __restrict__ G0,
                                               float* __restrict__ G2){
  int tid = threadIdx.x, w = tid >> 6, l = tid & 63;
  size_t n = (size_t)blockIdx.x*4 + w;
  const ushort* xr = XB + n*1024;
  int k0 = l * 16;
  float s0 = 0.f, s2 = 0.f;
  #pragma unroll
  for (int h = 0; h < 2; ++h){
    short8 xv = *(const short8*)&xr[k0 + h*8];
    #pragma unroll
    for (int e = 0; e < 8; ++e){
      float xf = bf2f((ushort)xv[e]);
      s0 += xf * Wg[(size_t)0*2048 + k0 + h*8 + e];
      s2 += xf * Wg[(size_t)2*2048 + k0 + h*8 + e];
    }
  }
  for (int off = 32; off; off >>= 1){ s0 += __shfl_xor(s0, off, 64); s2 += __shfl_xor(s2, off, 64); }
  if (l == 0){
    int b_i = (int)(n >> 9), t_i = (int)(n & 511);
    G0[(size_t)t_i*B_ + b_i] = s0 + bgv[0];
    G2[(size_t)t_i*B_ + b_i] = s2 + bgv[2];
  }
}

// ---------------- persistent recurrence: canary data-is-the-flag, 8-slot hot window ----------------
// 256 WGs: bg = blk&7 (16 batch rows), oc = blk>>3 (32 out cols). ~121KB LDS ->
// 1 WG/CU; grid==256==#CUs => co-resident. Whh slice + gate weights LDS-resident.
// hW[8 slots][B][1024] (2MB, MALL-resident; aliases dead XB region). Slot 0 = h0 =
// zeros; slots 1..7 canary-armed by memset. Producers write h pairs as relaxed
// agent-scope 4B stores (write-through to IF; R3/R7/R8-proven). Consumers poll
// their sc1 16B loads, retrying chunks containing CANARY (R8-proven, tripwire-
// clean). Slot reuse: in the epilogue of step t each producer re-arms its
// addresses in slot (t+3)&7. Safe because (a) that slot's value v_{t-5} was
// fully read >=5 steps ago (transitive barrier chain), (b) the arm store is
// drained by step t+1's staging vmcnt(0) BEFORE the v_{t+3} value store can
// issue (end of t+2) and before any consumer can reach step t+3 -- so stale
// pre-arm data is never observable. Time-bounded retries + sticky dead flag.
__global__ __launch_bounds__(256, 1) void k_recur(const ushort* __restrict__ Wcb,
                                                  const float*  __restrict__ Wg,
                                                  const ushort* __restrict__ A2,
                                                  const float*  __restrict__ G0,
                                                  const float*  __restrict__ G2,
                                                  const float*  __restrict__ alive,
                                                  ushort* __restrict__ hW,      // [8][B][1024]
                                                  float*  __restrict__ hsum,    // [B][1024]
                                                  uint*   __restrict__ bar){
  __shared__ ushort WhhS[32*1024];        // 64KB, XOR-swizzled rows (out-cols)
  __shared__ ushort hS[4*16*256];         // 32KB, [wave][row][k-slice], swizzled
  __shared__ ushort wgS[3*1032];          // 6.2KB: padded rows (wg0, wg2, zeros)
  __shared__ float  upart[2][4][16][33];  // 16.9KB, parity-double-buffered
  __shared__ float  gpart[2][4][16][2];   // 1KB

  const int blk = blockIdx.x;
  const int bg = blk & 7, oc = blk >> 3;
  const int tid = threadIdx.x, w = tid >> 6, l = tid & 63;
  const long long tstart = rtclock();

  // ---- prologue: Whh slice -> LDS (swizzled write) ----
  #pragma unroll
  for (int it = 0; it < 16; ++it){
    int ch = it*256 + tid;            // 4096 chunks of 16B
    int ci = ch >> 7;                 // local col 0..31
    int kb = (ch & 127) * 16;         // byte in 2048B row
    const char* src = (const char*)Wcb + (((size_t)(oc*32 + ci)*2048 + 1024) * 2) + kb;
    uint4 v = *(const uint4*)src;
    *(uint4*)((char*)WhhS + ci*2048 + (kb ^ ((ci & 7) << 4))) = v;
  }
  for (int it = 0; it < 13; ++it){
    int idx = it*256 + tid;           // 0..3095
    if (idx < 3096){
      int j = idx / 1032, k = idx - j*1032;
      float v = 0.f;
      if (k < 1024){
        if (j == 0)      v = Wg[(size_t)0*2048 + 1024 + k];
        else if (j == 1) v = Wg[(size_t)2*2048 + 1024 + k];
      }
      wgS[idx] = f2bf(v);
    }
  }
  __syncthreads();

  const int r_ep = tid >> 4;                 // epilogue row 0..15
  const int c0   = (tid & 15) * 2;           // epilogue col pair
  const int b_ep = bg*16 + r_ep;
  const int lr   = l & 15, lk = (l >> 4) * 8;
  const int gsel = (lr == 0) ? 0 : (lr == 2 ? 2064 : 4128);   // byte offset into wgS (padded rows)
  float hs0 = 0.f, hs1 = 0.f;

  uint* dead = &bar[BAR_DEAD];
  bool bail = false;

  // producer per-slot uint offset (same (row,col-pair) in every slot)
  uint* const hWu = (uint*)hW;
  const size_t pOff = (size_t)b_ep*512 + (size_t)(oc*16 + (tid & 15));
  const size_t slotU = (size_t)B_*512;       // uints per slot

  // prefetch step-0 inputs into registers
  uint  av  = *(const uint*)&A2[((size_t)0*B_ + b_ep)*1024 + oc*32 + c0];
  float gx0 = G0[b_ep], gx2 = G2[b_ep];
  float au  = alive[0];

  for (int t = 0; t < T_; ++t){
    // ---- poll+load wave-private h K-slice: sc1 16B loads, retry CANARY chunks ----
    const ushort* hprev = hW + (size_t)(t & (NSLOT-1))*(B_*H_) + (size_t)bg*16*1024;
    const char* ap[8];
    #pragma unroll
    for (int j = 0; j < 8; ++j){
      int r = j*2 + (l >> 5);
      int s = l & 31;
      ap[j] = (const char*)(hprev + (size_t)r*1024 + w*256 + ((s ^ (r & 7)) * 8));
    }
    uint4 hv[8];
    #pragma unroll
    for (int j = 0; j < 8; ++j)
      asm volatile("global_load_dwordx4 %0, %1, off sc1" : "=v"(hv[j]) : "v"(ap[j]));
    asm volatile("s_waitcnt vmcnt(0)" ::: "memory");
    uint pend = 0;
    #pragma unroll
    for (int j = 0; j < 8; ++j)
      if (hv[j].x == CANARY || hv[j].y == CANARY || hv[j].z == CANARY || hv[j].w == CANARY)
        pend |= (1u << j);
    if (!bail && __any((int)(pend != 0u))){
      long long t0 = rtclock();
      uint it = 0;
      while (__any((int)(pend != 0u))){
        #pragma unroll
        for (int j = 0; j < 8; ++j)
          if (pend & (1u << j))
            asm volatile("global_load_dwordx4 %0, %1, off sc1" : "=v"(hv[j]) : "v"(ap[j]));
        asm volatile("s_waitcnt vmcnt(0)" ::: "memory");
        #pragma unroll
        for (int j = 0; j < 8; ++j)
          if ((pend & (1u << j)) &&
              !(hv[j].x == CANARY || hv[j].y == CANARY || hv[j].z == CANARY || hv[j].w == CANARY))
            pend &= ~(1u << j);
        if ((++it & 15u) == 0u){
          if (__hip_atomic_load(dead, __ATOMIC_RELAXED, __HIP_MEMORY_SCOPE_AGENT)){ bail = true; break; }
          long long now = rtclock();
          if (now - t0 > 200000LL || now - tstart > 30000000LL){
            if (tid == 0) __hip_atomic_store(dead, 1u, __ATOMIC_RELAXED, __HIP_MEMORY_SCOPE_AGENT);
            bail = true; break;
          }
          __builtin_amdgcn_s_sleep(1);
        }
      }
    }
    #pragma unroll
    for (int j = 0; j < 8; ++j)
      *(uint4*)((char*)hS + w*8192 + j*1024 + (size_t)l*16) = hv[j];

    // ---- u + gates via MFMA (K split across waves) ----
    const int p = t & 1;
    f32x4 uacc0 = (f32x4){0.f,0.f,0.f,0.f};
    f32x4 uacc1 = (f32x4){0.f,0.f,0.f,0.f};
    f32x4 gacc  = (f32x4){0.f,0.f,0.f,0.f};
    #pragma unroll
    for (int ks = 0; ks < 8; ++ks){
      int kbh  = (ks*32 + lk) * 2;
      int swzh = kbh ^ ((lr & 7) << 4);
      short8 a  = *(const short8*)((const char*)hS + w*8192 + lr*512 + swzh);
      int kbw  = (w*256 + ks*32 + lk) * 2;
      int swzw = kbw ^ ((lr & 7) << 4);
      short8 b0 = *(const short8*)((const char*)WhhS + lr*2048 + swzw);
      short8 b1 = *(const short8*)((const char*)WhhS + (16 + lr)*2048 + swzw);
      short8 gv = *(const short8*)((const char*)wgS + gsel + kbw);
      uacc0 = __builtin_amdgcn_mfma_f32_16x16x32_bf16(a, b0, uacc0, 0, 0, 0);
      uacc1 = __builtin_amdgcn_mfma_f32_16x16x32_bf16(a, b1, uacc1, 0, 0, 0);
      gacc  = __builtin_amdgcn_mfma_f32_16x16x32_bf16(a, gv, gacc,  0, 0, 0);
    }
    #pragma unroll
    for (int r4 = 0; r4 < 4; ++r4){
      int m = (l >> 4)*4 + r4;
      upart[p][w][m][lr]      = uacc0[r4];
      upart[p][w][m][16 + lr] = uacc1[r4];
      if (lr == 0) gpart[p][w][m][0] = gacc[r4];
      if (lr == 2) gpart[p][w][m][1] = gacc[r4];
    }
    __syncthreads();

    // ---- epilogue: 2 outputs per thread ----
    float u0 = upart[p][0][r_ep][c0]   + upart[p][1][r_ep][c0]   + upart[p][2][r_ep][c0]   + upart[p][3][r_ep][c0];
    float u1 = upart[p][0][r_ep][c0+1] + upart[p][1][r_ep][c0+1] + upart[p][2][r_ep][c0+1] + upart[p][3][r_ep][c0+1];
    float gp0 = gpart[p][0][r_ep][0] + gpart[p][1][r_ep][0] + gpart[p][2][r_ep][0] + gpart[p][3][r_ep][0];
    float gp2 = gpart[p][0][r_ep][1] + gpart[p][1][r_ep][1] + gpart[p][2][r_ep][1] + gpart[p][3][r_ep][1];
    float gi = fsig(gx0 + gp0);
    float go = fsig(gx2 + gp2);
    float a0 = bf2f((ushort)(av & 0xffffu));
    float a1 = bf2f((ushort)(av >> 16));
    float hn0 = go * ftanh(gi * ftanh(a0 + u0));
    float hn1 = go * ftanh(gi * ftanh(a1 + u1));
    hs0 += au * hn0;
    hs1 += au * hn1;
    // publish v_{t+1} into slot (t+1)&7 (write-through agent store, R8-proven)
    uint hv2 = (uint)f2bf(hn0) | ((uint)f2bf(hn1) << 16);
    __hip_atomic_store(&hWu[(size_t)((t + 1) & (NSLOT-1))*slotU + pOff], hv2,
                       __ATOMIC_RELAXED, __HIP_MEMORY_SCOPE_AGENT);
    // re-arm canary in slot (t+3)&7 (drained by next step's staging vmcnt(0)
    // before the v_{t+3} store can issue; old value there was read at step t-5)
    if (t < T_-3)
      __hip_atomic_store(&hWu[(size_t)((t + 3) & (NSLOT-1))*slotU + pOff], CANARY,
                         __ATOMIC_RELAXED, __HIP_MEMORY_SCOPE_AGENT);

    // ---- prefetch next step's read-only inputs ----
    int tn = (t < T_-1) ? t + 1 : t;
    av  = *(const uint*)&A2[((size_t)tn*B_ + b_ep)*1024 + oc*32 + c0];
    gx0 = G0[(size_t)tn*B_ + b_ep];
    gx2 = G2[(size_t)tn*B_ + b_ep];
    au  = alive[tn];
  }

  hsum[(size_t)b_ep*1024 + oc*32 + c0]     = hs0;
  hsum[(size_t)b_ep*1024 + oc*32 + c0 + 1] = hs1;
}

// ---------------- output: out[b][c] = dot(hsum[b], Wo[c]) / aliveSum + bo[c] ----------------
__global__ __launch_bounds__(256) void k_out(const float* __restrict__ hsum,
                                             const float* __restrict__ Wo,
                                             const float* __restrict__ bo,
                                             const float* __restrict__ aliveSum,
                                             float* __restrict__ out){
  __shared__ float accs[NC_];
  int b = blockIdx.x, tid = threadIdx.x;
  if (tid < NC_) accs[tid] = 0.f;
  __syncthreads();
  int k0 = tid * 4;
  float4 hv = *(const float4*)&hsum[(size_t)b*1024 + k0];
  float part[NC_];
  #pragma unroll
  for (int c = 0; c < NC_; ++c){
    const float* wr = Wo + (size_t)c*1024 + k0;
    part[c] = hv.x*wr[0] + hv.y*wr[1] + hv.z*wr[2] + hv.w*wr[3];
  }
  #pragma unroll
  for (int c = 0; c < NC_; ++c){
    float v = part[c];
    for (int off = 32; off; off >>= 1) v += __shfl_xor(v, off, 64);
    if ((tid & 63) == 0) atomicAdd(&accs[c], v);
  }
  __syncthreads();
  if (tid < NC_) out[b*NC_ + tid] = accs[tid] / aliveSum[0] + bo[tid];
}

extern "C" void kernel_launch(void* const* d_in, const int* in_sizes, int n_in,
                              void* d_out, int out_size, void* d_ws, size_t ws_size,
                              hipStream_t stream){
  const int*   x     = (const int*)  d_in[0];
  const float* embed = (const float*)d_in[1];
  const float* Wg    = (const float*)d_in[2];
  const float* bg    = (const float*)d_in[3];
  const float* Wc    = (const float*)d_in[4];
  const float* bc    = (const float*)d_in[5];
  const float* Wo    = (const float*)d_in[6];
  const float* bo    = (const float*)d_in[7];
  float* out = (float*)d_out;

  // workspace layout (~274 MB). hW (8 h slots, 2MB) ALIASES XB: XB is dead after
  // k_gemmA/k_gateG; hW memsets below are stream-ordered after those kernels.
  char* p = (char*)d_ws;
  ushort* XB    = (ushort*)p;
  ushort* hW    = (ushort*)p;  p += (size_t)NT_*1024*2;     // 134.2MB (XB | hW)
  ushort* A2    = (ushort*)p;  p += (size_t)NT_*1024*2;     // 134.2MB  [t][b][1024]
  ushort* Wcb   = (ushort*)p;  p += (size_t)1024*2048*2;    // 4MB
  float*  G0    = (float*)p;   p += (size_t)NT_*4;          // 256KB
  float*  G2    = (float*)p;   p += (size_t)NT_*4;          // 256KB
  float*  hsum  = (float*)p;   p += (size_t)B_*H_*4;        // 512KB
  float*  alive = (float*)p;   p += (size_t)T_*4;
  float*  aliveSum = (float*)p; p += 256;
  uint*   bar   = (uint*)p;    p += 4*1024;                 // dead flag

  (void)ws_size; (void)in_sizes; (void)n_in; (void)out_size;

  hipMemsetAsync(bar, 0, 4*1024, stream);

  k_alive <<<1,    512, 0, stream>>>(x, alive, aliveSum);
  k_convW <<<8192, 256, 0, stream>>>(Wc, Wcb);
  k_gather<<<4096, 256, 0, stream>>>(x, embed, XB);
  k_gemmA <<<4096, 256, 0, stream>>>(XB, Wcb, bc, A2);
  k_gateG <<<16384,256, 0, stream>>>(XB, Wg, bg, G0, G2);

  // XB now dead; initialize the 8-slot h window in its place (stream-ordered):
  hipMemsetAsync(hW, 0xFF, (size_t)NSLOT*B_*H_*2, stream);   // slots: canary
  hipMemsetAsync(hW, 0,    (size_t)B_*H_*2, stream);         // slot 0: h0 = 0

  k_recur<<<256, 256, 0, stream>>>(Wcb, Wg, A2, G0, G2, alive, hW, hsum, bar);

  k_out<<<B_, 256, 0, stream>>>(hsum, Wo, bo, aliveSum, out);
}

// Round 11
// 2082.678 us; speedup vs baseline: 1.1200x; 1.0658x over previous
//
#include <hip/hip_runtime.h>
#include <hip/hip_bf16.h>
#include <stdint.h>

#define B_  128
#define T_  512
#define H_  1024
#define E_  1024
#define NC_ 10
#define NT_ (B_*T_)   // 65536

// bar[] layout (uint indices): dead flag, then per-wave step flags
#define BAR_DEAD  0
#define BAR_FLAGS 256   // + bg*2048 + (oc*4 + wave)*16

typedef __attribute__((ext_vector_type(8))) short  short8;
typedef __attribute__((ext_vector_type(4))) float  f32x4;

static __device__ __forceinline__ float bf2f(ushort u){
  union { uint u; float f; } v; v.u = ((uint)u) << 16; return v.f;
}
static __device__ __forceinline__ ushort f2bf(float f){
  union { float f; uint u; } v; v.f = f;
  uint u = v.u;
  uint lsb = (u >> 16) & 1u;
  u += 0x7fffu + lsb;          // round-to-nearest-even
  return (ushort)(u >> 16);
}
static __device__ __forceinline__ float fsig(float x){ return 1.f / (1.f + __expf(-x)); }
static __device__ __forceinline__ float ftanh(float x){
  float e = __expf(2.f * x);
  return 1.f - 2.f / (e + 1.f);
}

// async global->LDS, 16B per lane. LDS dst wave-uniform; HW adds lane*16. Global src per-lane.
#define ASYNC_COPY16(gsrc, ldsdst) \
  __builtin_amdgcn_global_load_lds((const __attribute__((address_space(1))) uint32_t*)(gsrc), \
                                   (__attribute__((address_space(3))) uint32_t*)(ldsdst), 16, 0, 0)

static __device__ __forceinline__ long long rtclock(){
  return (long long)__builtin_amdgcn_s_memrealtime();
}

// ---------------- alive[t] = cumprod(colsum(x) != 0) ----------------
__global__ __launch_bounds__(512) void k_alive(const int* __restrict__ x,
                                               float* __restrict__ alive,
                                               float* __restrict__ aliveSum){
  __shared__ float fl[T_];
  int t = threadIdx.x;
  int s = 0;
  for (int b = 0; b < B_; ++b) s += x[b*T_ + t];
  fl[t] = (s != 0) ? 1.f : 0.f;
  __syncthreads();
  if (t == 0){
    float run = 1.f, sum = 0.f;
    for (int i = 0; i < T_; ++i){ run *= fl[i]; alive[i] = run; sum += run; }
    aliveSum[0] = sum;
  }
}

// ---------------- weight conversion: Wc -> bf16 (stride 2048) ----------------
__global__ __launch_bounds__(256) void k_convW(const float* __restrict__ Wc,
                                               ushort* __restrict__ Wcb){
  int idx = blockIdx.x*256 + threadIdx.x;
  if (idx < 1024*2048) Wcb[idx] = f2bf(Wc[idx]);
}

// ---------------- gather + bf16 convert: XB[n][k] = bf16(embed[x[n]][k]) ----------------
__global__ __launch_bounds__(256) void k_gather(const int* __restrict__ x,
                                                const float* __restrict__ embed,
                                                ushort* __restrict__ XB){
  size_t g = (size_t)blockIdx.x*256 + threadIdx.x;
  const size_t total = (size_t)NT_ * 128;   // 8-element chunks
  for (; g < total; g += (size_t)gridDim.x*256){
    size_t row = g >> 7;
    int cj = (int)(g & 127) * 8;
    int tok = x[row];
    const float* src = embed + (size_t)tok*1024 + cj;
    float4 v0 = *(const float4*)src;
    float4 v1 = *(const float4*)(src + 4);
    uint4 o;
    o.x = (uint)f2bf(v0.x) | ((uint)f2bf(v0.y) << 16);
    o.y = (uint)f2bf(v0.z) | ((uint)f2bf(v0.w) << 16);
    o.z = (uint)f2bf(v1.x) | ((uint)f2bf(v1.y) << 16);
    o.w = (uint)f2bf(v1.z) | ((uint)f2bf(v1.w) << 16);
    *(uint4*)&XB[g*8] = o;
  }
}

// ---------------- big GEMM: A2[t][b][o] = bf16( sum_k XB[n][k]*Wcb[o][k] + bc[o] ), n=b*T+t ----------------
__global__ __launch_bounds__(256) void k_gemmA(const ushort* __restrict__ XB,
                                               const ushort* __restrict__ Wcb,
                                               const float* __restrict__ bc,
                                               ushort* __restrict__ A2){
  __shared__ ushort As[128*64];
  __shared__ ushort Bs[128*64];
  const int bx = blockIdx.x;
  const int nt = bx & 7, mt = bx >> 3;
  const int tid = threadIdx.x, w = tid >> 6, l = tid & 63;
  const int wm = w >> 1, wn = w & 1;
  f32x4 acc[4][4];
  #pragma unroll
  for (int i = 0; i < 4; ++i)
    #pragma unroll
    for (int j = 0; j < 4; ++j) acc[i][j] = (f32x4){0.f,0.f,0.f,0.f};

  const int lrow = l >> 3, lcol = (l & 7) * 8;
  for (int kt = 0; kt < 16; ++kt){
    #pragma unroll
    for (int i = 0; i < 4; ++i){
      int cc = i*4 + w;
      const ushort* ga = XB  + (size_t)(mt*128 + cc*8 + lrow)*1024 + kt*64 + lcol;
      ASYNC_COPY16(ga, (char*)As + cc*1024);
      const ushort* gb = Wcb + (size_t)(nt*128 + cc*8 + lrow)*2048 + kt*64 + lcol;
      ASYNC_COPY16(gb, (char*)Bs + cc*1024);
    }
    __syncthreads();
    #pragma unroll
    for (int ks = 0; ks < 2; ++ks){
      short8 a[4], b[4];
      #pragma unroll
      for (int mi = 0; mi < 4; ++mi)
        a[mi] = *(const short8*)&As[(wm*64 + mi*16 + (l & 15))*64 + ks*32 + (l >> 4)*8];
      #pragma unroll
      for (int ni = 0; ni < 4; ++ni)
        b[ni] = *(const short8*)&Bs[(wn*64 + ni*16 + (l & 15))*64 + ks*32 + (l >> 4)*8];
      #pragma unroll
      for (int mi = 0; mi < 4; ++mi)
        #pragma unroll
        for (int ni = 0; ni < 4; ++ni)
          acc[mi][ni] = __builtin_amdgcn_mfma_f32_16x16x32_bf16(a[mi], b[ni], acc[mi][ni], 0, 0, 0);
    }
    __syncthreads();
  }
  const int col0 = nt*128 + wn*64;
  const int row0 = mt*128 + wm*64;
  #pragma unroll
  for (int ni = 0; ni < 4; ++ni){
    int col = col0 + ni*16 + (l & 15);
    float bias = bc[col];
    #pragma unroll
    for (int mi = 0; mi < 4; ++mi)
      #pragma unroll
      for (int r = 0; r < 4; ++r){
        int row = row0 + mi*16 + (l >> 4)*4 + r;   // n = b*T + t
        int b_i = row >> 9, t_i = row & 511;
        A2[((size_t)t_i*B_ + b_i)*1024 + col] = f2bf(acc[mi][ni][r] + bias);
      }
  }
}

// ---------------- gate x-part: G0/G2[t*B+b] = sum_k XB[n][k]*Wg[j][k] + bg[j], j in {0,2} ----------------
__global__ __launch_bounds__(256) void k_gateG(const ushort* __restrict__ XB,
                                               const float* __restrict__ Wg,
                                               const float* __restrict__ bgv,
                                               float* __restrict__ G0,
                                               float* __restrict__ G2){
  int tid = threadIdx.x, w = tid >> 6, l = tid & 63;
  size_t n = (size_t)blockIdx.x*4 + w;
  const ushort* xr = XB + n*1024;
  int k0 = l * 16;
  float s0 = 0.f, s2 = 0.f;
  #pragma unroll
  for (int h = 0; h < 2; ++h){
    short8 xv = *(const short8*)&xr[k0 + h*8];
    #pragma unroll
    for (int e = 0; e < 8; ++e){
      float xf = bf2f((ushort)xv[e]);
      s0 += xf * Wg[(size_t)0*2048 + k0 + h*8 + e];
      s2 += xf * Wg[(size_t)2*2048 + k0 + h*8 + e];
    }
  }
  for (int off = 32; off; off >>= 1){ s0 += __shfl_xor(s0, off, 64); s2 += __shfl_xor(s2, off, 64); }
  if (l == 0){
    int b_i = (int)(n >> 9), t_i = (int)(n & 511);
    G0[(size_t)t_i*B_ + b_i] = s0 + bgv[0];
    G2[(size_t)t_i*B_ + b_i] = s2 + bgv[2];
  }
}

// ---------------- persistent recurrence: R7 protocol + per-wave flags + &15 swizzle ----------------
// 256 WGs: bg = blk&7 (16 batch rows), oc = blk>>3 (32 out cols). ~121KB LDS ->
// 1 WG/CU; grid==256==#CUs => co-resident. Whh slice + gate weights LDS-resident.
// h via IF: relaxed agent atomic stores (write-through, R3/R7-proven) + sc1 loads.
// Per-WAVE flags: wave drains its own h stores (vmcnt0) then signals its flag slot;
// consumer wave w polls 32 flags (its 8 producers oc'=8w..8w+7 x 4 waves).
// Safety of 2-slot h ping-pong with per-wave flags: each WG's pre-epilogue
// __syncthreads joins all 4 waves' polls BEFORE any h write; signal follows the
// signaler's staging reads; so when any producer writes slot (t+1)&1 (holding
// v_{t-1}), every WG of the group has finished reading v_{t-1}. No WAR hazard.
// upart/gpart parity-double-buffered -> post-epilogue barrier removed.
// Time-bounded spins + sticky dead flag: never a wedge.
__global__ __launch_bounds__(256, 1) void k_recur(const ushort* __restrict__ Wcb,
                                                  const float*  __restrict__ Wg,
                                                  const ushort* __restrict__ A2,
                                                  const float*  __restrict__ G0,
                                                  const float*  __restrict__ G2,
                                                  const float*  __restrict__ alive,
                                                  ushort* __restrict__ hglob,   // [2][B][1024]
                                                  float*  __restrict__ hsum,    // [B][1024]
                                                  uint*   __restrict__ bar){
  __shared__ ushort WhhS[32*1024];        // 64KB, XOR-swizzled rows (&15 key)
  __shared__ ushort hS[4*16*256];         // 32KB, [wave][row][k-slice], swizzled (&15)
  __shared__ ushort wgS[3*1032];          // 6.2KB: padded rows (wg0, wg2, zeros)
  __shared__ float  upart[2][4][16][33];  // 16.9KB, parity-double-buffered
  __shared__ float  gpart[2][4][16][2];   // 1KB

  const int blk = blockIdx.x;
  const int bg = blk & 7, oc = blk >> 3;
  const int tid = threadIdx.x, w = tid >> 6, l = tid & 63;
  const long long tstart = rtclock();

  // ---- prologue: Whh slice -> LDS (swizzled write, key = row&15) ----
  #pragma unroll
  for (int it = 0; it < 16; ++it){
    int ch = it*256 + tid;            // 4096 chunks of 16B
    int ci = ch >> 7;                 // local col 0..31
    int kb = (ch & 127) * 16;         // byte in 2048B row
    const char* src = (const char*)Wcb + (((size_t)(oc*32 + ci)*2048 + 1024) * 2) + kb;
    uint4 v = *(const uint4*)src;
    *(uint4*)((char*)WhhS + ci*2048 + (kb ^ ((ci & 15) << 4))) = v;
  }
  for (int it = 0; it < 13; ++it){
    int idx = it*256 + tid;           // 0..3095
    if (idx < 3096){
      int j = idx / 1032, k = idx - j*1032;
      float v = 0.f;
      if (k < 1024){
        if (j == 0)      v = Wg[(size_t)0*2048 + 1024 + k];
        else if (j == 1) v = Wg[(size_t)2*2048 + 1024 + k];
      }
      wgS[idx] = f2bf(v);
    }
  }
  __syncthreads();

  const int r_ep = tid >> 4;                 // epilogue row 0..15
  const int c0   = (tid & 15) * 2;           // epilogue col pair
  const int b_ep = bg*16 + r_ep;
  const int lr   = l & 15, lk = (l >> 4) * 8;
  const int gsel = (lr == 0) ? 0 : (lr == 2 ? 2064 : 4128);   // byte offset into wgS (padded rows)
  float hs0 = 0.f, hs1 = 0.f;

  uint* dead  = &bar[BAR_DEAD];
  uint* flags = &bar[BAR_FLAGS + bg*2048];
  // consumer poll address: producers oc' = 8w + (l>>2), wave vi = l&3  (l < 32)
  const uint* myflag = &flags[(((w << 3) | (l >> 2)) * 4 + (l & 3)) * 16];
  // producer signal slot for THIS wave
  uint* sigflag = &flags[((oc * 4) + w) * 16];
  bool bail = false;

  // prefetch step-0 inputs into registers
  uint  av  = *(const uint*)&A2[((size_t)0*B_ + b_ep)*1024 + oc*32 + c0];
  float gx0 = G0[b_ep], gx2 = G2[b_ep];
  float au  = alive[0];

  for (int t = 0; t < T_; ++t){
    // ---- wait: all 4 waves of this wave's 8 producers finished step t-1 ----
    if (t > 0 && !bail){
      const uint tgt = (uint)t;
      long long t0 = rtclock();
      uint it = 0;
      while (true){
        uint v = tgt;
        if (l < 32) v = __hip_atomic_load(myflag, __ATOMIC_RELAXED, __HIP_MEMORY_SCOPE_AGENT);
        if (__all((int)(v >= tgt))) break;
        if ((++it & 63u) == 0u){
          if (__hip_atomic_load(dead, __ATOMIC_RELAXED, __HIP_MEMORY_SCOPE_AGENT)){ bail = true; break; }
          long long now = rtclock();
          if (now - t0 > 4000000LL || now - tstart > 1000000000LL){
            if (l == 0) __hip_atomic_store(dead, 1u, __ATOMIC_RELAXED, __HIP_MEMORY_SCOPE_AGENT);
            bail = true; break;
          }
        }
        __builtin_amdgcn_s_sleep(1);
      }
    }

    // ---- stage wave-private h K-slice: sc1 loads -> regs -> LDS (&15 swizzle) ----
    const ushort* hprev = hglob + (size_t)(t & 1)*B_*H_ + (size_t)bg*16*1024;
    uint4 hv[8];
    #pragma unroll
    for (int j = 0; j < 8; ++j){
      int r = j*2 + (l >> 5);
      int s = l & 31;
      const void* src = hprev + (size_t)r*1024 + w*256 + ((s ^ (r & 15)) * 8);
      asm volatile("global_load_dwordx4 %0, %1, off sc1" : "=v"(hv[j]) : "v"(src));
    }
    asm volatile("s_waitcnt vmcnt(0)" ::: "memory");
    __builtin_amdgcn_sched_barrier(0);
    #pragma unroll
    for (int j = 0; j < 8; ++j)
      *(uint4*)((char*)hS + w*8192 + j*1024 + (size_t)l*16) = hv[j];

    // ---- u + gates via MFMA (K split across waves) ----
    const int p = t & 1;
    f32x4 uacc0 = (f32x4){0.f,0.f,0.f,0.f};
    f32x4 uacc1 = (f32x4){0.f,0.f,0.f,0.f};
    f32x4 gacc  = (f32x4){0.f,0.f,0.f,0.f};
    #pragma unroll
    for (int ks = 0; ks < 8; ++ks){
      int kbh  = (ks*32 + lk) * 2;
      int swzh = kbh ^ ((lr & 15) << 4);
      short8 a  = *(const short8*)((const char*)hS + w*8192 + lr*512 + swzh);
      int kbw  = (w*256 + ks*32 + lk) * 2;
      int swzw = kbw ^ ((lr & 15) << 4);
      short8 b0 = *(const short8*)((const char*)WhhS + lr*2048 + swzw);
      short8 b1 = *(const short8*)((const char*)WhhS + (16 + lr)*2048 + swzw);
      short8 gv = *(const short8*)((const char*)wgS + gsel + kbw);
      uacc0 = __builtin_amdgcn_mfma_f32_16x16x32_bf16(a, b0, uacc0, 0, 0, 0);
      uacc1 = __builtin_amdgcn_mfma_f32_16x16x32_bf16(a, b1, uacc1, 0, 0, 0);
      gacc  = __builtin_amdgcn_mfma_f32_16x16x32_bf16(a, gv, gacc,  0, 0, 0);
    }
    #pragma unroll
    for (int r4 = 0; r4 < 4; ++r4){
      int m = (l >> 4)*4 + r4;
      upart[p][w][m][lr]      = uacc0[r4];
      upart[p][w][m][16 + lr] = uacc1[r4];
      if (lr == 0) gpart[p][w][m][0] = gacc[r4];
      if (lr == 2) gpart[p][w][m][1] = gacc[r4];
    }
    __syncthreads();   // joins all 4 waves' polls + upart/gpart visibility

    // ---- epilogue: 2 outputs per thread ----
    float u0 = upart[p][0][r_ep][c0]   + upart[p][1][r_ep][c0]   + upart[p][2][r_ep][c0]   + upart[p][3][r_ep][c0];
    float u1 = upart[p][0][r_ep][c0+1] + upart[p][1][r_ep][c0+1] + upart[p][2][r_ep][c0+1] + upart[p][3][r_ep][c0+1];
    float gp0 = gpart[p][0][r_ep][0] + gpart[p][1][r_ep][0] + gpart[p][2][r_ep][0] + gpart[p][3][r_ep][0];
    float gp2 = gpart[p][0][r_ep][1] + gpart[p][1][r_ep][1] + gpart[p][2][r_ep][1] + gpart[p][3][r_ep][1];
    float gi = fsig(gx0 + gp0);
    float go = fsig(gx2 + gp2);
    float a0 = bf2f((ushort)(av & 0xffffu));
    float a1 = bf2f((ushort)(av >> 16));
    float hn0 = go * ftanh(gi * ftanh(a0 + u0));
    float hn1 = go * ftanh(gi * ftanh(a1 + u1));
    hs0 += au * hn0;
    hs1 += au * hn1;
    // write-through h store to the coherence point (R3/R7-proven)
    uint hv2 = (uint)f2bf(hn0) | ((uint)f2bf(hn1) << 16);
    uint* hdst = (uint*)&hglob[(size_t)((t + 1) & 1)*B_*H_ + (size_t)b_ep*1024 + oc*32 + c0];
    __hip_atomic_store(hdst, hv2, __ATOMIC_RELAXED, __HIP_MEMORY_SCOPE_AGENT);

    // ---- per-wave signal: drain THIS wave's h stores, then publish ----
    asm volatile("s_waitcnt vmcnt(0)" ::: "memory");
    if (l == 0 && t < T_-1)
      __hip_atomic_store(sigflag, (uint)(t + 1), __ATOMIC_RELAXED, __HIP_MEMORY_SCOPE_AGENT);

    // ---- prefetch next step's read-only inputs (hides under next poll) ----
    int tn = (t < T_-1) ? t + 1 : t;
    av  = *(const uint*)&A2[((size_t)tn*B_ + b_ep)*1024 + oc*32 + c0];
    gx0 = G0[(size_t)tn*B_ + b_ep];
    gx2 = G2[(size_t)tn*B_ + b_ep];
    au  = alive[tn];
  }

  hsum[(size_t)b_ep*1024 + oc*32 + c0]     = hs0;
  hsum[(size_t)b_ep*1024 + oc*32 + c0 + 1] = hs1;
}

// ---------------- output: out[b][c] = dot(hsum[b], Wo[c]) / aliveSum + bo[c] ----------------
__global__ __launch_bounds__(256) void k_out(const float* __restrict__ hsum,
                                             const float* __restrict__ Wo,
                                             const float* __restrict__ bo,
                                             const float* __restrict__ aliveSum,
                                             float* __restrict__ out){
  __shared__ float accs[NC_];
  int b = blockIdx.x, tid = threadIdx.x;
  if (tid < NC_) accs[tid] = 0.f;
  __syncthreads();
  int k0 = tid * 4;
  float4 hv = *(const float4*)&hsum[(size_t)b*1024 + k0];
  float part[NC_];
  #pragma unroll
  for (int c = 0; c < NC_; ++c){
    const float* wr = Wo + (size_t)c*1024 + k0;
    part[c] = hv.x*wr[0] + hv.y*wr[1] + hv.z*wr[2] + hv.w*wr[3];
  }
  #pragma unroll
  for (int c = 0; c < NC_; ++c){
    float v = part[c];
    for (int off = 32; off; off >>= 1) v += __shfl_xor(v, off, 64);
    if ((tid & 63) == 0) atomicAdd(&accs[c], v);
  }
  __syncthreads();
  if (tid < NC_) out[b*NC_ + tid] = accs[tid] / aliveSum[0] + bo[tid];
}

extern "C" void kernel_launch(void* const* d_in, const int* in_sizes, int n_in,
                              void* d_out, int out_size, void* d_ws, size_t ws_size,
                              hipStream_t stream){
  const int*   x     = (const int*)  d_in[0];
  const float* embed = (const float*)d_in[1];
  const float* Wg    = (const float*)d_in[2];
  const float* bg    = (const float*)d_in[3];
  const float* Wc    = (const float*)d_in[4];
  const float* bc    = (const float*)d_in[5];
  const float* Wo    = (const float*)d_in[6];
  const float* bo    = (const float*)d_in[7];
  float* out = (float*)d_out;

  // workspace layout (~274 MB)
  char* p = (char*)d_ws;
  ushort* XB    = (ushort*)p;  p += (size_t)NT_*1024*2;     // 134.2MB
  ushort* A2    = (ushort*)p;  p += (size_t)NT_*1024*2;     // 134.2MB  [t][b][1024]
  ushort* Wcb   = (ushort*)p;  p += (size_t)1024*2048*2;    // 4MB
  float*  G0    = (float*)p;   p += (size_t)NT_*4;          // 256KB
  float*  G2    = (float*)p;   p += (size_t)NT_*4;          // 256KB
  ushort* hglob = (ushort*)p;  p += (size_t)2*B_*H_*2;      // 512KB
  float*  hsum  = (float*)p;   p += (size_t)B_*H_*4;        // 512KB
  float*  alive = (float*)p;   p += (size_t)T_*4;
  float*  aliveSum = (float*)p; p += 256;
  uint*   bar   = (uint*)p;    p += 128*1024;               // dead + per-wave flags

  (void)ws_size; (void)in_sizes; (void)n_in; (void)out_size;

  hipMemsetAsync(hglob, 0, (size_t)B_*H_*2, stream);   // h0 = 0 (buffer slot 0)
  hipMemsetAsync(bar,   0, 128*1024, stream);          // dead + flags

  k_alive <<<1,    512, 0, stream>>>(x, alive, aliveSum);
  k_convW <<<8192, 256, 0, stream>>>(Wc, Wcb);
  k_gather<<<4096, 256, 0, stream>>>(x, embed, XB);
  k_gemmA <<<4096, 256, 0, stream>>>(XB, Wcb, bc, A2);
  k_gateG <<<16384,256, 0, stream>>>(XB, Wg, bg, G0, G2);

  k_recur<<<256, 256, 0, stream>>>(Wcb, Wg, A2, G0, G2, alive, hglob, hsum, bar);

  k_out<<<B_, 256, 0, stream>>>(hsum, Wo, bo, aliveSum, out);
}

// Round 13
// 1736.287 us; speedup vs baseline: 1.3435x; 1.1995x over previous
//
#include <hip/hip_runtime.h>
#include <hip/hip_bf16.h>
#include <stdint.h>

#define B_  128
#define T_  512
#define H_  1024
#define E_  1024
#define NC_ 10
#define NT_ (B_*T_)   // 65536

// bar[] layout (uint indices): step flags [8 groups][32 slots x 16], then dead
#define BAR_STEP  0
#define BAR_DEAD  4096

typedef __attribute__((ext_vector_type(8))) short  short8;
typedef __attribute__((ext_vector_type(4))) float  f32x4;

static __device__ __forceinline__ float bf2f(ushort u){
  union { uint u; float f; } v; v.u = ((uint)u) << 16; return v.f;
}
static __device__ __forceinline__ ushort f2bf(float f){
  union { float f; uint u; } v; v.f = f;
  uint u = v.u;
  uint lsb = (u >> 16) & 1u;
  u += 0x7fffu + lsb;          // round-to-nearest-even
  return (ushort)(u >> 16);
}
static __device__ __forceinline__ float fsig(float x){ return 1.f / (1.f + __expf(-x)); }
static __device__ __forceinline__ float ftanh(float x){
  float e = __expf(2.f * x);
  return 1.f - 2.f / (e + 1.f);
}

// async global->LDS, 16B per lane. LDS dst wave-uniform; HW adds lane*16. Global src per-lane.
#define ASYNC_COPY16(gsrc, ldsdst) \
  __builtin_amdgcn_global_load_lds((const __attribute__((address_space(1))) uint32_t*)(gsrc), \
                                   (__attribute__((address_space(3))) uint32_t*)(ldsdst), 16, 0, 0)

static __device__ __forceinline__ long long rtclock(){
  return (long long)__builtin_amdgcn_s_memrealtime();
}

// ---------------- alive[t] = cumprod(colsum(x) != 0) ----------------
__global__ __launch_bounds__(512) void k_alive(const int* __restrict__ x,
                                               float* __restrict__ alive,
                                               float* __restrict__ aliveSum){
  __shared__ float fl[T_];
  int t = threadIdx.x;
  int s = 0;
  for (int b = 0; b < B_; ++b) s += x[b*T_ + t];
  fl[t] = (s != 0) ? 1.f : 0.f;
  __syncthreads();
  if (t == 0){
    float run = 1.f, sum = 0.f;
    for (int i = 0; i < T_; ++i){ run *= fl[i]; alive[i] = run; sum += run; }
    aliveSum[0] = sum;
  }
}

// ---------------- weight conversion: Wc -> bf16 (stride 2048) ----------------
__global__ __launch_bounds__(256) void k_convW(const float* __restrict__ Wc,
                                               ushort* __restrict__ Wcb){
  int idx = blockIdx.x*256 + threadIdx.x;
  if (idx < 1024*2048) Wcb[idx] = f2bf(Wc[idx]);
}

// ---------------- gather + bf16 convert: XB[n][k] = bf16(embed[x[n]][k]) ----------------
__global__ __launch_bounds__(256) void k_gather(const int* __restrict__ x,
                                                const float* __restrict__ embed,
                                                ushort* __restrict__ XB){
  size_t g = (size_t)blockIdx.x*256 + threadIdx.x;
  const size_t total = (size_t)NT_ * 128;   // 8-element chunks
  for (; g < total; g += (size_t)gridDim.x*256){
    size_t row = g >> 7;
    int cj = (int)(g & 127) * 8;
    int tok = x[row];
    const float* src = embed + (size_t)tok*1024 + cj;
    float4 v0 = *(const float4*)src;
    float4 v1 = *(const float4*)(src + 4);
    uint4 o;
    o.x = (uint)f2bf(v0.x) | ((uint)f2bf(v0.y) << 16);
    o.y = (uint)f2bf(v0.z) | ((uint)f2bf(v0.w) << 16);
    o.z = (uint)f2bf(v1.x) | ((uint)f2bf(v1.y) << 16);
    o.w = (uint)f2bf(v1.z) | ((uint)f2bf(v1.w) << 16);
    *(uint4*)&XB[g*8] = o;
  }
}

// ---------------- big GEMM: A2[t][b][o] = bf16( sum_k XB[n][k]*Wcb[o][k] + bc[o] ), n=b*T+t ----------------
__global__ __launch_bounds__(256) void k_gemmA(const ushort* __restrict__ XB,
                                               const ushort* __restrict__ Wcb,
                                               const float* __restrict__ bc,
                                               ushort* __restrict__ A2){
  __shared__ ushort As[128*64];
  __shared__ ushort Bs[128*64];
  const int bx = blockIdx.x;
  const int nt = bx & 7, mt = bx >> 3;
  const int tid = threadIdx.x, w = tid >> 6, l = tid & 63;
  const int wm = w >> 1, wn = w & 1;
  f32x4 acc[4][4];
  #pragma unroll
  for (int i = 0; i < 4; ++i)
    #pragma unroll
    for (int j = 0; j < 4; ++j) acc[i][j] = (f32x4){0.f,0.f,0.f,0.f};

  const int lrow = l >> 3, lcol = (l & 7) * 8;
  for (int kt = 0; kt < 16; ++kt){
    #pragma unroll
    for (int i = 0; i < 4; ++i){
      int cc = i*4 + w;
      const ushort* ga = XB  + (size_t)(mt*128 + cc*8 + lrow)*1024 + kt*64 + lcol;
      ASYNC_COPY16(ga, (char*)As + cc*1024);
      const ushort* gb = Wcb + (size_t)(nt*128 + cc*8 + lrow)*2048 + kt*64 + lcol;
      ASYNC_COPY16(gb, (char*)Bs + cc*1024);
    }
    __syncthreads();
    #pragma unroll
    for (int ks = 0; ks < 2; ++ks){
      short8 a[4], b[4];
      #pragma unroll
      for (int mi = 0; mi < 4; ++mi)
        a[mi] = *(const short8*)&As[(wm*64 + mi*16 + (l & 15))*64 + ks*32 + (l >> 4)*8];
      #pragma unroll
      for (int ni = 0; ni < 4; ++ni)
        b[ni] = *(const short8*)&Bs[(wn*64 + ni*16 + (l & 15))*64 + ks*32 + (l >> 4)*8];
      #pragma unroll
      for (int mi = 0; mi < 4; ++mi)
        #pragma unroll
        for (int ni = 0; ni < 4; ++ni)
          acc[mi][ni] = __builtin_amdgcn_mfma_f32_16x16x32_bf16(a[mi], b[ni], acc[mi][ni], 0, 0, 0);
    }
    __syncthreads();
  }
  const int col0 = nt*128 + wn*64;
  const int row0 = mt*128 + wm*64;
  #pragma unroll
  for (int ni = 0; ni < 4; ++ni){
    int col = col0 + ni*16 + (l & 15);
    float bias = bc[col];
    #pragma unroll
    for (int mi = 0; mi < 4; ++mi)
      #pragma unroll
      for (int r = 0; r < 4; ++r){
        int row = row0 + mi*16 + (l >> 4)*4 + r;   // n = b*T + t
        int b_i = row >> 9, t_i = row & 511;
        A2[((size_t)t_i*B_ + b_i)*1024 + col] = f2bf(acc[mi][ni][r] + bias);
      }
  }
}

// ---------------- gate x-part: G0/G2[t*B+b] = sum_k XB[n][k]*Wg[j][k] + bg[j], j in {0,2} ----------------
__global__ __launch_bounds__(256) void k_gateG(const ushort* __restrict__ XB,
                                               const float* __restrict__ Wg,
                                               const float* __restrict__ bgv,
                                               float* __restrict__ G0,
                                               float* __restrict__ G2){
  int tid = threadIdx.x, w = tid >> 6, l = tid & 63;
  size_t n = (size_t)blockIdx.x*4 + w;
  const ushort* xr = XB + n*1024;
  int k0 = l * 16;
  float s0 = 0.f, s2 = 0.f;
  #pragma unroll
  for (int h = 0; h < 2; ++h){
    short8 xv = *(const short8*)&xr[k0 + h*8];
    #pragma unroll
    for (int e = 0; e < 8; ++e){
      float xf = bf2f((ushort)xv[e]);
      s0 += xf * Wg[(size_t)0*2048 + k0 + h*8 + e];
      s2 += xf * Wg[(size_t)2*2048 + k0 + h*8 + e];
    }
  }
  for (int off = 32; off; off >>= 1){ s0 += __shfl_xor(s0, off, 64); s2 += __shfl_xor(s2, off, 64); }
  if (l == 0){
    int b_i = (int)(n >> 9), t_i = (int)(n & 511);
    G0[(size_t)t_i*B_ + b_i] = s0 + bgv[0];
    G2[(size_t)t_i*B_ + b_i] = s2 + bgv[2];
  }
}

// ---------------- persistent recurrence: R7 protocol (proven 1453us) + &15 swizzle ----------------
// Identical to R12 (recombination of two individually-passed kernels); R12's bench
// died with an infra-pattern container failure (3rd on the same pod; R7/R11 with the
// same primitives passed). Resubmit with tightened spin budgets (4ms/poll, 2s total).
__global__ __launch_bounds__(256, 1) void k_recur(const ushort* __restrict__ Wcb,
                                                  const float*  __restrict__ Wg,
                                                  const ushort* __restrict__ A2,
                                                  const float*  __restrict__ G0,
                                                  const float*  __restrict__ G2,
                                                  const float*  __restrict__ alive,
                                                  ushort* __restrict__ hglob,   // [2][B][1024]
                                                  float*  __restrict__ hsum,    // [B][1024]
                                                  uint*   __restrict__ bar){
  __shared__ ushort WhhS[32*1024];      // 64KB, XOR-swizzled rows (&15 key)
  __shared__ ushort hS[4*16*256];       // 32KB, [wave][row][k-slice], swizzled (&15)
  __shared__ ushort wgS[3*1032];        // 6.2KB: padded rows (wg0, wg2, zeros)
  __shared__ float  upart[4][16][33];   // 8448B cross-wave K-partials (odd stride)
  __shared__ float  gpart[4][16][2];    // gate K-partials

  const int blk = blockIdx.x;
  const int bg = blk & 7, oc = blk >> 3;
  const int tid = threadIdx.x, w = tid >> 6, l = tid & 63;
  const long long tstart = rtclock();

  // ---- prologue: Whh slice -> LDS (swizzled write, key = row&15) ----
  #pragma unroll
  for (int it = 0; it < 16; ++it){
    int ch = it*256 + tid;            // 4096 chunks of 16B
    int ci = ch >> 7;                 // local col 0..31
    int kb = (ch & 127) * 16;         // byte in 2048B row
    const char* src = (const char*)Wcb + (((size_t)(oc*32 + ci)*2048 + 1024) * 2) + kb;
    uint4 v = *(const uint4*)src;
    *(uint4*)((char*)WhhS + ci*2048 + (kb ^ ((ci & 15) << 4))) = v;
  }
  for (int it = 0; it < 13; ++it){
    int idx = it*256 + tid;           // 0..3095
    if (idx < 3096){
      int j = idx / 1032, k = idx - j*1032;
      float v = 0.f;
      if (k < 1024){
        if (j == 0)      v = Wg[(size_t)0*2048 + 1024 + k];
        else if (j == 1) v = Wg[(size_t)2*2048 + 1024 + k];
      }
      wgS[idx] = f2bf(v);
    }
  }
  __syncthreads();

  const int r_ep = tid >> 4;                 // epilogue row 0..15
  const int c0   = (tid & 15) * 2;           // epilogue col pair
  const int b_ep = bg*16 + r_ep;
  const int lr   = l & 15, lk = (l >> 4) * 8;
  const int gsel = (lr == 0) ? 0 : (lr == 2 ? 2064 : 4128);   // byte offset into wgS (padded rows)
  float hs0 = 0.f, hs1 = 0.f;

  uint* flags = &bar[BAR_STEP + bg*512];
  uint* dead  = &bar[BAR_DEAD];
  const uint* myflag = &flags[((w << 3) | (l & 7)) * 16];  // this wave's 8 producers
  bool bail = false;

  // prefetch step-0 inputs into registers
  uint  av  = *(const uint*)&A2[((size_t)0*B_ + b_ep)*1024 + oc*32 + c0];
  float gx0 = G0[b_ep], gx2 = G2[b_ep];
  float au  = alive[0];

  for (int t = 0; t < T_; ++t){
    // ---- wait: this wave's 8 producers finished step t-1 (per-wave poll, no fence) ----
    if (t > 0 && !bail){
      const uint tgt = (uint)t;
      long long t0 = rtclock();
      uint it = 0;
      while (true){
        uint v = tgt;
        if (l < 8) v = __hip_atomic_load(myflag, __ATOMIC_RELAXED, __HIP_MEMORY_SCOPE_AGENT);
        if (__all((int)(v >= tgt))) break;
        if ((++it & 63u) == 0u){
          if (__hip_atomic_load(dead, __ATOMIC_RELAXED, __HIP_MEMORY_SCOPE_AGENT)){ bail = true; break; }
          long long now = rtclock();
          if (now - t0 > 400000LL || now - tstart > 200000000LL){
            if (l == 0) __hip_atomic_store(dead, 1u, __ATOMIC_RELAXED, __HIP_MEMORY_SCOPE_AGENT);
            bail = true; break;
          }
        }
        __builtin_amdgcn_s_sleep(2);
      }
    }

    // ---- stage wave-private h K-slice: sc1 loads -> regs -> LDS (&15 swizzle) ----
    const ushort* hprev = hglob + (size_t)(t & 1)*B_*H_ + (size_t)bg*16*1024;
    uint4 hv[8];
    #pragma unroll
    for (int j = 0; j < 8; ++j){
      int r = j*2 + (l >> 5);
      int s = l & 31;
      const void* src = hprev + (size_t)r*1024 + w*256 + ((s ^ (r & 15)) * 8);
      asm volatile("global_load_dwordx4 %0, %1, off sc1" : "=v"(hv[j]) : "v"(src));
    }
    asm volatile("s_waitcnt vmcnt(0)" ::: "memory");
    __builtin_amdgcn_sched_barrier(0);
    #pragma unroll
    for (int j = 0; j < 8; ++j)
      *(uint4*)((char*)hS + w*8192 + j*1024 + (size_t)l*16) = hv[j];

    // ---- u + gates via MFMA (K split across waves) ----
    f32x4 uacc0 = (f32x4){0.f,0.f,0.f,0.f};
    f32x4 uacc1 = (f32x4){0.f,0.f,0.f,0.f};
    f32x4 gacc  = (f32x4){0.f,0.f,0.f,0.f};
    #pragma unroll
    for (int ks = 0; ks < 8; ++ks){
      int kbh  = (ks*32 + lk) * 2;
      int swzh = kbh ^ ((lr & 15) << 4);
      short8 a  = *(const short8*)((const char*)hS + w*8192 + lr*512 + swzh);
      int kbw  = (w*256 + ks*32 + lk) * 2;
      int swzw = kbw ^ ((lr & 15) << 4);
      short8 b0 = *(const short8*)((const char*)WhhS + lr*2048 + swzw);
      short8 b1 = *(const short8*)((const char*)WhhS + (16 + lr)*2048 + swzw);
      short8 gv = *(const short8*)((const char*)wgS + gsel + kbw);
      uacc0 = __builtin_amdgcn_mfma_f32_16x16x32_bf16(a, b0, uacc0, 0, 0, 0);
      uacc1 = __builtin_amdgcn_mfma_f32_16x16x32_bf16(a, b1, uacc1, 0, 0, 0);
      gacc  = __builtin_amdgcn_mfma_f32_16x16x32_bf16(a, gv, gacc,  0, 0, 0);
    }
    #pragma unroll
    for (int r4 = 0; r4 < 4; ++r4){
      int m = (l >> 4)*4 + r4;
      upart[w][m][lr]      = uacc0[r4];
      upart[w][m][16 + lr] = uacc1[r4];
      if (lr == 0) gpart[w][m][0] = gacc[r4];
      if (lr == 2) gpart[w][m][1] = gacc[r4];
    }
    __syncthreads();

    // ---- epilogue: 2 outputs per thread ----
    float u0 = upart[0][r_ep][c0]   + upart[1][r_ep][c0]   + upart[2][r_ep][c0]   + upart[3][r_ep][c0];
    float u1 = upart[0][r_ep][c0+1] + upart[1][r_ep][c0+1] + upart[2][r_ep][c0+1] + upart[3][r_ep][c0+1];
    float gp0 = gpart[0][r_ep][0] + gpart[1][r_ep][0] + gpart[2][r_ep][0] + gpart[3][r_ep][0];
    float gp2 = gpart[0][r_ep][1] + gpart[1][r_ep][1] + gpart[2][r_ep][1] + gpart[3][r_ep][1];
    float gi = fsig(gx0 + gp0);
    float go = fsig(gx2 + gp2);
    float a0 = bf2f((ushort)(av & 0xffffu));
    float a1 = bf2f((ushort)(av >> 16));
    float hn0 = go * ftanh(gi * ftanh(a0 + u0));
    float hn1 = go * ftanh(gi * ftanh(a1 + u1));
    hs0 += au * hn0;
    hs1 += au * hn1;
    // write-through h store to the coherence point (R3/R7-proven)
    uint hv2 = (uint)f2bf(hn0) | ((uint)f2bf(hn1) << 16);
    uint* hdst = (uint*)&hglob[(size_t)((t + 1) & 1)*B_*H_ + (size_t)b_ep*1024 + oc*32 + c0];
    __hip_atomic_store(hdst, hv2, __ATOMIC_RELAXED, __HIP_MEMORY_SCOPE_AGENT);

    // ---- prefetch next step's read-only inputs (overlaps the store drain) ----
    int tn = (t < T_-1) ? t + 1 : t;
    av  = *(const uint*)&A2[((size_t)tn*B_ + b_ep)*1024 + oc*32 + c0];
    gx0 = G0[(size_t)tn*B_ + b_ep];
    gx2 = G2[(size_t)tn*B_ + b_ep];
    au  = alive[tn];

    // ---- signal: all waves' h stores drained by the barrier's vmcnt(0) ----
    __syncthreads();
    if (tid == 0 && t < T_-1)
      __hip_atomic_store(&flags[oc*16], (uint)(t + 1), __ATOMIC_RELAXED, __HIP_MEMORY_SCOPE_AGENT);
  }

  hsum[(size_t)b_ep*1024 + oc*32 + c0]     = hs0;
  hsum[(size_t)b_ep*1024 + oc*32 + c0 + 1] = hs1;
}

// ---------------- output: out[b][c] = dot(hsum[b], Wo[c]) / aliveSum + bo[c] ----------------
__global__ __launch_bounds__(256) void k_out(const float* __restrict__ hsum,
                                             const float* __restrict__ Wo,
                                             const float* __restrict__ bo,
                                             const float* __restrict__ aliveSum,
                                             float* __restrict__ out){
  __shared__ float accs[NC_];
  int b = blockIdx.x, tid = threadIdx.x;
  if (tid < NC_) accs[tid] = 0.f;
  __syncthreads();
  int k0 = tid * 4;
  float4 hv = *(const float4*)&hsum[(size_t)b*1024 + k0];
  float part[NC_];
  #pragma unroll
  for (int c = 0; c < NC_; ++c){
    const float* wr = Wo + (size_t)c*1024 + k0;
    part[c] = hv.x*wr[0] + hv.y*wr[1] + hv.z*wr[2] + hv.w*wr[3];
  }
  #pragma unroll
  for (int c = 0; c < NC_; ++c){
    float v = part[c];
    for (int off = 32; off; off >>= 1) v += __shfl_xor(v, off, 64);
    if ((tid & 63) == 0) atomicAdd(&accs[c], v);
  }
  __syncthreads();
  if (tid < NC_) out[b*NC_ + tid] = accs[tid] / aliveSum[0] + bo[tid];
}

extern "C" void kernel_launch(void* const* d_in, const int* in_sizes, int n_in,
                              void* d_out, int out_size, void* d_ws, size_t ws_size,
                              hipStream_t stream){
  const int*   x     = (const int*)  d_in[0];
  const float* embed = (const float*)d_in[1];
  const float* Wg    = (const float*)d_in[2];
  const float* bg    = (const float*)d_in[3];
  const float* Wc    = (const float*)d_in[4];
  const float* bc    = (const float*)d_in[5];
  const float* Wo    = (const float*)d_in[6];
  const float* bo    = (const float*)d_in[7];
  float* out = (float*)d_out;

  // workspace layout (~274 MB)
  char* p = (char*)d_ws;
  ushort* XB    = (ushort*)p;  p += (size_t)NT_*1024*2;     // 134.2MB
  ushort* A2    = (ushort*)p;  p += (size_t)NT_*1024*2;     // 134.2MB  [t][b][1024]
  ushort* Wcb   = (ushort*)p;  p += (size_t)1024*2048*2;    // 4MB
  float*  G0    = (float*)p;   p += (size_t)NT_*4;          // 256KB
  float*  G2    = (float*)p;   p += (size_t)NT_*4;          // 256KB
  ushort* hglob = (ushort*)p;  p += (size_t)2*B_*H_*2;      // 512KB
  float*  hsum  = (float*)p;   p += (size_t)B_*H_*4;        // 512KB
  float*  alive = (float*)p;   p += (size_t)T_*4;
  float*  aliveSum = (float*)p; p += 256;
  uint*   bar   = (uint*)p;    p += 64*1024;                // step flags + dead

  (void)ws_size; (void)in_sizes; (void)n_in; (void)out_size;

  hipMemsetAsync(hglob, 0, (size_t)B_*H_*2, stream);   // h0 = 0 (buffer slot 0)
  hipMemsetAsync(bar,   0, 64*1024, stream);           // barrier state

  k_alive <<<1,    512, 0, stream>>>(x, alive, aliveSum);
  k_convW <<<8192, 256, 0, stream>>>(Wc, Wcb);
  k_gather<<<4096, 256, 0, stream>>>(x, embed, XB);
  k_gemmA <<<4096, 256, 0, stream>>>(XB, Wcb, bc, A2);
  k_gateG <<<16384,256, 0, stream>>>(XB, Wg, bg, G0, G2);

  k_recur<<<256, 256, 0, stream>>>(Wcb, Wg, A2, G0, G2, alive, hglob, hsum, bar);

  k_out<<<B_, 256, 0, stream>>>(hsum, Wo, bo, aliveSum, out);
}